// Round 6
// baseline (373.681 us; speedup 1.0000x reference)
//
#include <hip/hip_runtime.h>
#include <hip/hip_bf16.h>
#include <stdint.h>

#define B_ 2
#define N_ 4096
#define D_ 128
#define H_ 4
#define HID_ 32
#define EN_ 16
#define ALPHA_ 0.2f
#define S1_ 8          // split-K factor, layer-1 attention
#define S2_ 8          // split-K factor, layer-2 attention
#define LOG2E_ 1.4426950408889634f

typedef __attribute__((ext_vector_type(8))) short bf16x8;
typedef __attribute__((ext_vector_type(4))) float f32x4;
typedef __attribute__((ext_vector_type(8))) unsigned short u16x8;

__device__ __forceinline__ float bf2f(unsigned short u) {
    return __uint_as_float(((unsigned int)u) << 16);
}
__device__ __forceinline__ unsigned short f2bf_rne(float x) {
    unsigned int u = __float_as_uint(x);
    unsigned int r = ((u >> 16) & 1u) + 0x7fffu;
    return (unsigned short)((u + r) >> 16);
}
// monotonic float->uint key for atomicMax over signed floats
__device__ __forceinline__ unsigned int f2key(float x) {
    unsigned int u = __float_as_uint(x);
    return (u & 0x80000000u) ? ~u : (u | 0x80000000u);
}
__device__ __forceinline__ float key2f(unsigned int k) {
    unsigned int u = (k & 0x80000000u) ? (k ^ 0x80000000u) : ~k;
    return __uint_as_float(u);
}

// ---------- layer-1 projection: wh[b][h][i][d] = fea[b][i][:] @ W_heads[h][:][d]
__global__ __launch_bounds__(256) void proj1_kernel(
    const float* __restrict__ fea, const float* __restrict__ Wh,
    float* __restrict__ wh)
{
    __shared__ float Ws[D_ * HID_];   // 16 KB
    __shared__ float xs[8][D_];       // 4 KB
    const int b = blockIdx.z, h = blockIdx.y;
    const int i0 = blockIdx.x * 8;
    const int tid = threadIdx.x;
    const float* Wp = Wh + h * D_ * HID_;
    for (int idx = tid * 4; idx < D_ * HID_; idx += 1024)
        *(float4*)&Ws[idx] = *(const float4*)(Wp + idx);
    const float* xp = fea + ((size_t)b * N_ + i0) * D_;
    *(float4*)&xs[(tid * 4) >> 7][(tid * 4) & 127] = *(const float4*)(xp + tid * 4);
    __syncthreads();
    const int r = tid >> 5, d = tid & 31;
    float acc = 0.f;
#pragma unroll 8
    for (int k = 0; k < D_; ++k) acc += xs[r][k] * Ws[k * HID_ + d];
    wh[(((size_t)b * H_ + h) * N_ + i0 + r) * HID_ + d] = acc;
}

// ---------- layer-1: wh1, wh2 (scaled by log2e), per-(b,h) max, bf16 whTt[b][h][jblk][32][64]
__global__ __launch_bounds__(128) void proj1b_kernel(
    const float* __restrict__ wh, const float* __restrict__ a_heads,
    float* __restrict__ wh1, float* __restrict__ wh2,
    unsigned int* __restrict__ mkey, unsigned short* __restrict__ whTt)
{
    __shared__ float as_[2 * HID_];
    __shared__ unsigned short ts[32][136];   // row = 272 B (16-aligned for b128)
    const int b = blockIdx.z, h = blockIdx.y, tid = threadIdx.x;
    const int i = blockIdx.x * 128 + tid;
    if (tid < 2 * HID_) as_[tid] = a_heads[h * 2 * HID_ + tid];
    __syncthreads();
    const float* row = wh + (((size_t)b * H_ + h) * N_ + i) * HID_;
    float rv[32];
#pragma unroll
    for (int q = 0; q < 8; ++q) *(float4*)&rv[q * 4] = ((const float4*)row)[q];
    float a1 = 0.f, a2 = 0.f;
#pragma unroll
    for (int d = 0; d < HID_; ++d) {
        float v = rv[d];
        a1 += v * as_[d]; a2 += v * as_[HID_ + d];
        ts[d][tid] = f2bf_rne(v);
    }
    a1 *= LOG2E_; a2 *= LOG2E_;     // prescale: exp(x) -> exp2(x'), lrelu is +scale-invariant
    const size_t o = (size_t)(b * H_ + h) * N_ + i;
    wh1[o] = a1; wh2[o] = a2;
    float m = a2;
#pragma unroll
    for (int off = 32; off; off >>= 1) m = fmaxf(m, __shfl_xor(m, off));
    if ((tid & 63) == 0) atomicMax(&mkey[b * H_ + h], f2key(m));
    __syncthreads();
    const size_t base = ((size_t)(b * H_ + h) * 64 + blockIdx.x * 2) * 2048;
#pragma unroll
    for (int r = 0; r < 4; ++r) {
        int l = r * 128 + tid;               // 0..511
        int jb = l >> 8, d = (l >> 3) & 31, part = l & 7;
        *(u16x8*)(whTt + base + (size_t)jb * 2048 + d * 64 + part * 8) =
            *(const u16x8*)&ts[d][jb * 64 + part * 8];
    }
}

// ---------- layer-1 fused MFMA attention, zero-LDS, split-K, heads merged per wave.
// block 256 = 4 independent waves; wave = 16 rows x 512 j x 4 heads.
__global__ __launch_bounds__(256) void attn1_kernel(
    const float* __restrict__ adj, const unsigned short* __restrict__ whT,
    const float* __restrict__ wh1, const float* __restrict__ wh2,
    const unsigned int* __restrict__ mkey,
    float* __restrict__ x2num, float* __restrict__ l1sum)
{
    const int b = blockIdx.z, split = blockIdx.y;
    const int tid = threadIdx.x, lane = tid & 63, wv = tid >> 6;
    const int i0 = blockIdx.x * 64 + wv * 16;
    const int m = lane & 15, quad = lane >> 4;
    const int jb0 = split * (N_ / S1_ / 64);          // 8 tiles per split
    float w1r[H_], mr[H_];
    const float* w2h[H_];
    const unsigned short* whTp[H_];
#pragma unroll
    for (int h = 0; h < H_; ++h) {
        w1r[h] = wh1[(size_t)(b * H_ + h) * N_ + i0 + m];
        float Mh = key2f(mkey[b * H_ + h]);
        float sb = w1r[h] + Mh;
        mr[h] = fmaxf(sb, ALPHA_ * sb);               // lrelu == max(s, 0.2s)
        w2h[h] = wh2 + (size_t)(b * H_ + h) * N_;
        whTp[h] = whT + (size_t)(b * H_ + h) * 64 * 2048;
    }
    const float* adjr = adj + ((size_t)b * N_ + i0 + m) * N_;
    f32x4 acc0[H_], acc1[H_];
    float lsum[H_];
#pragma unroll
    for (int h = 0; h < H_; ++h) {
        acc0[h] = (f32x4){0.f, 0.f, 0.f, 0.f};
        acc1[h] = (f32x4){0.f, 0.f, 0.f, 0.f};
        lsum[h] = 0.f;
    }

    for (int t = 0; t < N_ / S1_ / 64; ++t) {
        const int jb = jb0 + t;
#pragma unroll
        for (int ks = 0; ks < 2; ++ks) {
            const int jo = (jb << 6) + ks * 32 + quad * 8;
            float av[8];
            *(float4*)&av[0] = *(const float4*)(adjr + jo);
            *(float4*)&av[4] = *(const float4*)(adjr + jo + 4);
#pragma unroll
            for (int h = 0; h < H_; ++h) {
                float wv8[8];
                *(float4*)&wv8[0] = *(const float4*)(w2h[h] + jo);
                *(float4*)&wv8[4] = *(const float4*)(w2h[h] + jo + 4);
                bf16x8 af;
#pragma unroll
                for (int jj = 0; jj < 8; ++jj) {
                    float s = w1r[h] + wv8[jj];
                    float e = fmaxf(s, ALPHA_ * s);
                    float tt = (av[jj] == 0.f || s == 0.f) ? -__builtin_inff()
                                                           : (e - mr[h]);
                    float p = __builtin_amdgcn_exp2f(tt);
                    unsigned short pb = f2bf_rne(p);
                    af[jj] = (short)pb;
                    lsum[h] += bf2f(pb);             // consistent with MFMA numerator
                }
                const unsigned short* bp =
                    whTp[h] + (size_t)jb * 2048 + m * 64 + ks * 32 + quad * 8;
                bf16x8 b0 = *(const bf16x8*)bp;
                bf16x8 b1 = *(const bf16x8*)(bp + 1024);   // d = m+16
                acc0[h] = __builtin_amdgcn_mfma_f32_16x16x32_bf16(af, b0, acc0[h], 0, 0, 0);
                acc1[h] = __builtin_amdgcn_mfma_f32_16x16x32_bf16(af, b1, acc1[h], 0, 0, 0);
            }
        }
    }
    // numerator partials -> atomic accumulate
#pragma unroll
    for (int h = 0; h < H_; ++h) {
#pragma unroll
        for (int reg = 0; reg < 4; ++reg) {
            int row = quad * 4 + reg;                 // C/D: col=lane&15, row=quad*4+reg
            float* dst = x2num + ((size_t)b * N_ + i0 + row) * (H_ * HID_) + h * HID_;
            atomicAdd(dst + m, acc0[h][reg]);
            atomicAdd(dst + 16 + m, acc1[h][reg]);
        }
        lsum[h] += __shfl_xor(lsum[h], 16);
        lsum[h] += __shfl_xor(lsum[h], 32);
    }
    float lv = quad == 0 ? lsum[0] : quad == 1 ? lsum[1] : quad == 2 ? lsum[2] : lsum[3];
    atomicAdd(l1sum + ((size_t)b * N_ + i0 + m) * H_ + quad, lv);
}

// ---------- layer-2 projection with fused layer-1 finalize: whl2 = elu(x2num/l1) @ W_last
__global__ __launch_bounds__(256) void proj2_kernel(
    const float* __restrict__ x2num, const float* __restrict__ l1sum,
    const float* __restrict__ Wl, float* __restrict__ whl2)
{
    __shared__ float Ws[D_ * EN_];
    __shared__ float xs[16][D_];
    const int b = blockIdx.y, i0 = blockIdx.x * 16, tid = threadIdx.x;
    for (int idx = tid * 4; idx < D_ * EN_; idx += 1024)
        *(float4*)&Ws[idx] = *(const float4*)(Wl + idx);
    for (int idx = tid * 4; idx < 16 * D_; idx += 1024) {
        int r = idx >> 7, hd = idx & 127, h = hd >> 5;
        const size_t i = (size_t)b * N_ + i0 + r;
        float linv = 1.f / fmaxf(l1sum[i * H_ + h], 1e-30f);
        float4 v = *(const float4*)(x2num + i * D_ + hd);
        float o0 = v.x * linv, o1 = v.y * linv, o2 = v.z * linv, o3 = v.w * linv;
        xs[r][hd]     = o0 > 0.f ? o0 : expm1f(o0);
        xs[r][hd + 1] = o1 > 0.f ? o1 : expm1f(o1);
        xs[r][hd + 2] = o2 > 0.f ? o2 : expm1f(o2);
        xs[r][hd + 3] = o3 > 0.f ? o3 : expm1f(o3);
    }
    __syncthreads();
    const int r = tid >> 4, e = tid & 15;
    float acc = 0.f;
#pragma unroll 8
    for (int k = 0; k < D_; ++k) acc += xs[r][k] * Ws[k * EN_ + e];
    whl2[((size_t)b * N_ + i0 + r) * EN_ + e] = acc;
}

// ---------- layer-2: wh1b, wh2b (scaled), per-b max, bf16 whT2t[b][jblk][16][64]
__global__ __launch_bounds__(128) void proj2b_kernel(
    const float* __restrict__ whl2, const float* __restrict__ a_last,
    float* __restrict__ wh1b, float* __restrict__ wh2b,
    unsigned int* __restrict__ mkey2, unsigned short* __restrict__ whT2t)
{
    __shared__ float as_[2 * EN_];
    __shared__ unsigned short ts[16][136];   // row = 272 B (16-aligned)
    const int b = blockIdx.y, tid = threadIdx.x;
    const int i = blockIdx.x * 128 + tid;
    if (tid < 2 * EN_) as_[tid] = a_last[tid];
    __syncthreads();
    const float* row = whl2 + ((size_t)b * N_ + i) * EN_;
    float rv[16];
#pragma unroll
    for (int q = 0; q < 4; ++q) *(float4*)&rv[q * 4] = ((const float4*)row)[q];
    float a1 = 0.f, a2 = 0.f;
#pragma unroll
    for (int e = 0; e < EN_; ++e) {
        float v = rv[e];
        a1 += v * as_[e]; a2 += v * as_[EN_ + e];
        ts[e][tid] = f2bf_rne(v);
    }
    a1 *= LOG2E_; a2 *= LOG2E_;
    wh1b[(size_t)b * N_ + i] = a1; wh2b[(size_t)b * N_ + i] = a2;
    float m = a2;
#pragma unroll
    for (int off = 32; off; off >>= 1) m = fmaxf(m, __shfl_xor(m, off));
    if ((tid & 63) == 0) atomicMax(mkey2 + b, f2key(m));
    __syncthreads();
    const size_t base = ((size_t)b * 64 + blockIdx.x * 2) * 1024;
#pragma unroll
    for (int r = 0; r < 2; ++r) {
        int l = r * 128 + tid;               // 0..255
        int jb = l >> 7, d = (l >> 3) & 15, part = l & 7;
        *(u16x8*)(whT2t + base + (size_t)jb * 1024 + d * 64 + part * 8) =
            *(const u16x8*)&ts[d][jb * 64 + part * 8];
    }
}

// ---------- layer-2 fused MFMA attention, zero-LDS, split-K
__global__ __launch_bounds__(256) void attn2_kernel(
    const float* __restrict__ adj, const unsigned short* __restrict__ whT2,
    const float* __restrict__ wh1b, const float* __restrict__ wh2b,
    const unsigned int* __restrict__ mkey2,
    float* __restrict__ out_num, float* __restrict__ out_l)
{
    const int b = blockIdx.z, split = blockIdx.y;
    const int tid = threadIdx.x, lane = tid & 63, wv = tid >> 6;
    const int i0 = blockIdx.x * 64 + wv * 16;
    const int m = lane & 15, quad = lane >> 4;
    const int jb0 = split * (N_ / S2_ / 64);
    const float w1r = wh1b[(size_t)b * N_ + i0 + m];
    const float Mh = key2f(mkey2[b]);
    const float sb = w1r + Mh;
    const float mr = fmaxf(sb, ALPHA_ * sb);
    const float* adjr = adj + ((size_t)b * N_ + i0 + m) * N_;
    const float* w2g = wh2b + (size_t)b * N_;
    const unsigned short* wTg = whT2 + (size_t)b * 64 * 1024;
    f32x4 acc = {0.f, 0.f, 0.f, 0.f};
    float lsum = 0.f;

    for (int t = 0; t < N_ / S2_ / 64; ++t) {
        const int jb = jb0 + t;
#pragma unroll
        for (int ks = 0; ks < 2; ++ks) {
            const int jo = (jb << 6) + ks * 32 + quad * 8;
            float av[8], wv8[8];
            *(float4*)&av[0] = *(const float4*)(adjr + jo);
            *(float4*)&av[4] = *(const float4*)(adjr + jo + 4);
            *(float4*)&wv8[0] = *(const float4*)(w2g + jo);
            *(float4*)&wv8[4] = *(const float4*)(w2g + jo + 4);
            bf16x8 af;
#pragma unroll
            for (int jj = 0; jj < 8; ++jj) {
                float s = w1r + wv8[jj];
                float e = fmaxf(s, ALPHA_ * s);
                float tt = (av[jj] == 0.f || s == 0.f) ? -__builtin_inff() : (e - mr);
                float p = __builtin_amdgcn_exp2f(tt);
                unsigned short pb = f2bf_rne(p);
                af[jj] = (short)pb;
                lsum += bf2f(pb);
            }
            bf16x8 b0 = *(const bf16x8*)(wTg + (size_t)jb * 1024 + m * 64 + ks * 32 + quad * 8);
            acc = __builtin_amdgcn_mfma_f32_16x16x32_bf16(af, b0, acc, 0, 0, 0);
        }
    }
#pragma unroll
    for (int reg = 0; reg < 4; ++reg) {
        int row = quad * 4 + reg;
        atomicAdd(out_num + ((size_t)b * N_ + i0 + row) * EN_ + m, acc[reg]);
    }
    lsum += __shfl_xor(lsum, 16);
    lsum += __shfl_xor(lsum, 32);
    if (quad == 0) atomicAdd(out_l + (size_t)b * N_ + i0 + m, lsum);
}

// ---------- final: out = elu(num / l)
__global__ __launch_bounds__(256) void finalize2_kernel(
    const float* __restrict__ num, const float* __restrict__ l, float* __restrict__ out)
{
    const int id = blockIdx.x * 256 + threadIdx.x;      // B*N*EN
    float v = num[id] / fmaxf(l[id >> 4], 1e-30f);
    out[id] = v > 0.f ? v : expm1f(v);
}

extern "C" void kernel_launch(void* const* d_in, const int* in_sizes, int n_in,
                              void* d_out, int out_size, void* d_ws, size_t ws_size,
                              hipStream_t stream)
{
    const float* fea = (const float*)d_in[0];
    const float* adj = (const float*)d_in[1];
    const float* Wh  = (const float*)d_in[2];
    const float* ah  = (const float*)d_in[3];
    const float* Wl  = (const float*)d_in[4];
    const float* al  = (const float*)d_in[5];

    float* ws    = (float*)d_ws;
    float* wh    = ws;                                   // B*H*N*HID = 1,048,576 f
    float* wh1   = wh   + (size_t)B_ * H_ * N_ * HID_;   // 32,768 f
    float* wh2   = wh1  + (size_t)B_ * H_ * N_;          // 32,768 f
    float* whl2  = wh2  + (size_t)B_ * H_ * N_;          // 131,072 f
    float* wh1b  = whl2 + (size_t)B_ * N_ * EN_;         // 8,192 f
    float* wh2b  = wh1b + (size_t)B_ * N_;               // 8,192 f
    // ---- zero region (single memset) ----
    float* x2num  = wh2b + (size_t)B_ * N_;              // B*N*128 = 1,048,576 f
    float* l1sum  = x2num + (size_t)B_ * N_ * D_;        // B*N*H = 32,768 f
    float* outnum = l1sum + (size_t)B_ * N_ * H_;        // B*N*EN = 131,072 f
    float* outl   = outnum + (size_t)B_ * N_ * EN_;      // B*N = 8,192 f
    unsigned int* mkey = (unsigned int*)(outl + (size_t)B_ * N_);  // 16 u32
    size_t zero_bytes = ((size_t)B_ * N_ * (D_ + H_ + EN_ + 1)) * 4 + 64;
    // ---- end zero region ----
    unsigned short* whTt  = (unsigned short*)(mkey + 16);          // 2 MB
    unsigned short* whT2t = whTt + (size_t)B_ * H_ * 64 * 2048;    // 256 KB

    hipMemsetAsync(x2num, 0, zero_bytes, stream);
    proj1_kernel<<<dim3(N_ / 8, H_, B_), 256, 0, stream>>>(fea, Wh, wh);
    proj1b_kernel<<<dim3(N_ / 128, H_, B_), 128, 0, stream>>>(wh, ah, wh1, wh2, mkey, whTt);
    attn1_kernel<<<dim3(N_ / 64, S1_, B_), 256, 0, stream>>>(adj, whTt, wh1, wh2, mkey,
                                                             x2num, l1sum);
    proj2_kernel<<<dim3(N_ / 16, B_), 256, 0, stream>>>(x2num, l1sum, Wl, whl2);
    proj2b_kernel<<<dim3(N_ / 128, B_), 128, 0, stream>>>(whl2, al, wh1b, wh2b, mkey + 8, whT2t);
    attn2_kernel<<<dim3(N_ / 64, S2_, B_), 256, 0, stream>>>(adj, whT2t, wh1b, wh2b, mkey + 8,
                                                             outnum, outl);
    finalize2_kernel<<<(B_ * N_ * EN_) / 256, 256, 0, stream>>>(outnum, outl, (float*)d_out);
}

// Round 7
// 314.074 us; speedup vs baseline: 1.1898x; 1.1898x over previous
//
#include <hip/hip_runtime.h>
#include <hip/hip_bf16.h>
#include <stdint.h>

#define B_ 2
#define N_ 4096
#define D_ 128
#define H_ 4
#define HID_ 32
#define EN_ 16
#define ALPHA_ 0.2f
#define S1_ 4          // split-K factor, layer-1 attention
#define S2_ 4          // split-K factor, layer-2 attention
#define LOG2E_ 1.4426950408889634f

typedef __attribute__((ext_vector_type(8))) short bf16x8;
typedef __attribute__((ext_vector_type(4))) float f32x4;
typedef __attribute__((ext_vector_type(8))) unsigned short u16x8;

__device__ __forceinline__ float bf2f(unsigned short u) {
    return __uint_as_float(((unsigned int)u) << 16);
}
__device__ __forceinline__ unsigned short f2bf_rne(float x) {
    unsigned int u = __float_as_uint(x);
    unsigned int r = ((u >> 16) & 1u) + 0x7fffu;
    return (unsigned short)((u + r) >> 16);
}
// monotonic float->uint key for atomicMax over signed floats
__device__ __forceinline__ unsigned int f2key(float x) {
    unsigned int u = __float_as_uint(x);
    return (u & 0x80000000u) ? ~u : (u | 0x80000000u);
}
__device__ __forceinline__ float key2f(unsigned int k) {
    unsigned int u = (k & 0x80000000u) ? (k ^ 0x80000000u) : ~k;
    return __uint_as_float(u);
}

// ---------- layer-1 projection: wh[b][h][i][d] = fea[b][i][:] @ W_heads[h][:][d]
__global__ __launch_bounds__(256) void proj1_kernel(
    const float* __restrict__ fea, const float* __restrict__ Wh,
    float* __restrict__ wh)
{
    __shared__ float Ws[D_ * HID_];   // 16 KB
    __shared__ float xs[8][D_];       // 4 KB
    const int b = blockIdx.z, h = blockIdx.y;
    const int i0 = blockIdx.x * 8;
    const int tid = threadIdx.x;
    const float* Wp = Wh + h * D_ * HID_;
    for (int idx = tid * 4; idx < D_ * HID_; idx += 1024)
        *(float4*)&Ws[idx] = *(const float4*)(Wp + idx);
    const float* xp = fea + ((size_t)b * N_ + i0) * D_;
    *(float4*)&xs[(tid * 4) >> 7][(tid * 4) & 127] = *(const float4*)(xp + tid * 4);
    __syncthreads();
    const int r = tid >> 5, d = tid & 31;
    float acc = 0.f;
#pragma unroll 8
    for (int k = 0; k < D_; ++k) acc += xs[r][k] * Ws[k * HID_ + d];
    wh[(((size_t)b * H_ + h) * N_ + i0 + r) * HID_ + d] = acc;
}

// ---------- layer-1: wh1, wh2 (scaled by log2e), per-(b,h) max, bf16 whTt[b][h][jblk][32][64]
__global__ __launch_bounds__(128) void proj1b_kernel(
    const float* __restrict__ wh, const float* __restrict__ a_heads,
    float* __restrict__ wh1, float* __restrict__ wh2,
    unsigned int* __restrict__ mkey, unsigned short* __restrict__ whTt)
{
    __shared__ float as_[2 * HID_];
    __shared__ unsigned short ts[32][136];   // row = 272 B (16-aligned for b128)
    const int b = blockIdx.z, h = blockIdx.y, tid = threadIdx.x;
    const int i = blockIdx.x * 128 + tid;
    if (tid < 2 * HID_) as_[tid] = a_heads[h * 2 * HID_ + tid];
    __syncthreads();
    const float* row = wh + (((size_t)b * H_ + h) * N_ + i) * HID_;
    float rv[32];
#pragma unroll
    for (int q = 0; q < 8; ++q) *(float4*)&rv[q * 4] = ((const float4*)row)[q];
    float a1 = 0.f, a2 = 0.f;
#pragma unroll
    for (int d = 0; d < HID_; ++d) {
        float v = rv[d];
        a1 += v * as_[d]; a2 += v * as_[HID_ + d];
        ts[d][tid] = f2bf_rne(v);
    }
    a1 *= LOG2E_; a2 *= LOG2E_;     // prescale: exp(x) -> exp2(x'), lrelu is +scale-invariant
    const size_t o = (size_t)(b * H_ + h) * N_ + i;
    wh1[o] = a1; wh2[o] = a2;
    float m = a2;
#pragma unroll
    for (int off = 32; off; off >>= 1) m = fmaxf(m, __shfl_xor(m, off));
    if ((tid & 63) == 0) atomicMax(&mkey[b * H_ + h], f2key(m));
    __syncthreads();
    const size_t base = ((size_t)(b * H_ + h) * 64 + blockIdx.x * 2) * 2048;
#pragma unroll
    for (int r = 0; r < 4; ++r) {
        int l = r * 128 + tid;               // 0..511
        int jb = l >> 8, d = (l >> 3) & 31, part = l & 7;
        *(u16x8*)(whTt + base + (size_t)jb * 2048 + d * 64 + part * 8) =
            *(const u16x8*)&ts[d][jb * 64 + part * 8];
    }
}

// ---------- layer-1 fused MFMA attention: heads merged (adj LDS reuse x4), split-K.
// block 256 = 4 waves (one per head), 16 rows/block, adj dbuf-staged coalesced.
__global__ __launch_bounds__(256) void attn1_kernel(
    const float* __restrict__ adj, const unsigned short* __restrict__ whT,
    const float* __restrict__ wh1, const float* __restrict__ wh2,
    const unsigned int* __restrict__ mkey,
    float* __restrict__ x2num, float* __restrict__ l1sum)
{
    __shared__ float adj_s[2][16][68];               // 8.7 KB dbuf
    const int b = blockIdx.z, split = blockIdx.y, i0 = blockIdx.x * 16;
    const int tid = threadIdx.x, lane = tid & 63, h = tid >> 6;   // wave = head
    const int m = lane & 15, quad = lane >> 4;
    const float w1r = wh1[(size_t)(b * H_ + h) * N_ + i0 + m];
    const float Mh = key2f(mkey[b * H_ + h]);
    const float sbound = w1r + Mh;
    const float mr = fmaxf(sbound, ALPHA_ * sbound); // lrelu == max(s, 0.2s)
    const float* adjb = adj + ((size_t)b * N_ + i0) * N_;
    const float* w2h = wh2 + (size_t)(b * H_ + h) * N_;
    const unsigned short* whTp = whT + (size_t)(b * H_ + h) * 64 * 2048;
    const int sr = tid >> 4, sc4 = (tid & 15) * 4;   // coalesced staging map
    f32x4 acc0 = {0.f, 0.f, 0.f, 0.f}, acc1 = {0.f, 0.f, 0.f, 0.f};
    float lsum = 0.f;
    const int TL = N_ / S1_ / 64;                    // 16 tiles per split
    const int jt0 = split * (N_ / S1_);

    auto stage = [&](int jt, int bufi) {
        *(float4*)&adj_s[bufi][sr][sc4] = *(const float4*)(adjb + (size_t)sr * N_ + jt + sc4);
    };
    stage(jt0, 0);
    int buf = 0;
    for (int t = 0; t < TL; ++t) {
        __syncthreads();
        if (t + 1 < TL) stage(jt0 + (t + 1) * 64, buf ^ 1);
        const int jt = jt0 + t * 64;
        const int jb = split * TL + t;
#pragma unroll
        for (int ks = 0; ks < 2; ++ks) {
            const int ko = ks * 32 + quad * 8;
            float av[8], wv8[8];
            *(float4*)&av[0] = *(const float4*)&adj_s[buf][m][ko];
            *(float4*)&av[4] = *(const float4*)&adj_s[buf][m][ko + 4];
            *(float4*)&wv8[0] = *(const float4*)(w2h + jt + ko);
            *(float4*)&wv8[4] = *(const float4*)(w2h + jt + ko + 4);
            bf16x8 af;
#pragma unroll
            for (int jj = 0; jj < 8; ++jj) {
                float s = w1r + wv8[jj];
                float e = fmaxf(s, ALPHA_ * s);
                float tt = (av[jj] == 0.f || s == 0.f) ? -__builtin_inff() : (e - mr);
                float p = __builtin_amdgcn_exp2f(tt);
                unsigned short pb = f2bf_rne(p);
                af[jj] = (short)pb;
                lsum += bf2f(pb);                    // consistent with MFMA numerator
            }
            const unsigned short* bp = whTp + (size_t)jb * 2048 + m * 64 + ks * 32 + quad * 8;
            bf16x8 b0 = *(const bf16x8*)bp;
            bf16x8 b1 = *(const bf16x8*)(bp + 1024);   // d = m+16
            acc0 = __builtin_amdgcn_mfma_f32_16x16x32_bf16(af, b0, acc0, 0, 0, 0);
            acc1 = __builtin_amdgcn_mfma_f32_16x16x32_bf16(af, b1, acc1, 0, 0, 0);
        }
        buf ^= 1;
    }
#pragma unroll
    for (int reg = 0; reg < 4; ++reg) {
        int row = quad * 4 + reg;                    // C/D: col=lane&15, row=quad*4+reg
        float* dst = x2num + ((size_t)b * N_ + i0 + row) * (H_ * HID_) + h * HID_;
        atomicAdd(dst + m, acc0[reg]);
        atomicAdd(dst + 16 + m, acc1[reg]);
    }
    lsum += __shfl_xor(lsum, 16);
    lsum += __shfl_xor(lsum, 32);                    // row-m total within this wave's split
    if (quad == 0) atomicAdd(l1sum + ((size_t)b * N_ + i0 + m) * H_ + h, lsum);
}

// ---------- layer-2 projection with fused layer-1 finalize: whl2 = elu(x2num/l1) @ W_last
__global__ __launch_bounds__(256) void proj2_kernel(
    const float* __restrict__ x2num, const float* __restrict__ l1sum,
    const float* __restrict__ Wl, float* __restrict__ whl2)
{
    __shared__ float Ws[D_ * EN_];
    __shared__ float xs[16][D_];
    const int b = blockIdx.y, i0 = blockIdx.x * 16, tid = threadIdx.x;
    for (int idx = tid * 4; idx < D_ * EN_; idx += 1024)
        *(float4*)&Ws[idx] = *(const float4*)(Wl + idx);
    for (int idx = tid * 4; idx < 16 * D_; idx += 1024) {
        int r = idx >> 7, hd = idx & 127, h = hd >> 5;
        const size_t i = (size_t)b * N_ + i0 + r;
        float linv = 1.f / fmaxf(l1sum[i * H_ + h], 1e-30f);
        float4 v = *(const float4*)(x2num + i * D_ + hd);
        float o0 = v.x * linv, o1 = v.y * linv, o2 = v.z * linv, o3 = v.w * linv;
        xs[r][hd]     = o0 > 0.f ? o0 : expm1f(o0);
        xs[r][hd + 1] = o1 > 0.f ? o1 : expm1f(o1);
        xs[r][hd + 2] = o2 > 0.f ? o2 : expm1f(o2);
        xs[r][hd + 3] = o3 > 0.f ? o3 : expm1f(o3);
    }
    __syncthreads();
    const int r = tid >> 4, e = tid & 15;
    float acc = 0.f;
#pragma unroll 8
    for (int k = 0; k < D_; ++k) acc += xs[r][k] * Ws[k * EN_ + e];
    whl2[((size_t)b * N_ + i0 + r) * EN_ + e] = acc;
}

// ---------- layer-2: wh1b, wh2b (scaled), per-b max, bf16 whT2t[b][jblk][16][64]
__global__ __launch_bounds__(128) void proj2b_kernel(
    const float* __restrict__ whl2, const float* __restrict__ a_last,
    float* __restrict__ wh1b, float* __restrict__ wh2b,
    unsigned int* __restrict__ mkey2, unsigned short* __restrict__ whT2t)
{
    __shared__ float as_[2 * EN_];
    __shared__ unsigned short ts[16][136];   // row = 272 B (16-aligned)
    const int b = blockIdx.y, tid = threadIdx.x;
    const int i = blockIdx.x * 128 + tid;
    if (tid < 2 * EN_) as_[tid] = a_last[tid];
    __syncthreads();
    const float* row = whl2 + ((size_t)b * N_ + i) * EN_;
    float rv[16];
#pragma unroll
    for (int q = 0; q < 4; ++q) *(float4*)&rv[q * 4] = ((const float4*)row)[q];
    float a1 = 0.f, a2 = 0.f;
#pragma unroll
    for (int e = 0; e < EN_; ++e) {
        float v = rv[e];
        a1 += v * as_[e]; a2 += v * as_[EN_ + e];
        ts[e][tid] = f2bf_rne(v);
    }
    a1 *= LOG2E_; a2 *= LOG2E_;
    wh1b[(size_t)b * N_ + i] = a1; wh2b[(size_t)b * N_ + i] = a2;
    float m = a2;
#pragma unroll
    for (int off = 32; off; off >>= 1) m = fmaxf(m, __shfl_xor(m, off));
    if ((tid & 63) == 0) atomicMax(mkey2 + b, f2key(m));
    __syncthreads();
    const size_t base = ((size_t)b * 64 + blockIdx.x * 2) * 1024;
#pragma unroll
    for (int r = 0; r < 2; ++r) {
        int l = r * 128 + tid;               // 0..255
        int jb = l >> 7, d = (l >> 3) & 15, part = l & 7;
        *(u16x8*)(whT2t + base + (size_t)jb * 1024 + d * 64 + part * 8) =
            *(const u16x8*)&ts[d][jb * 64 + part * 8];
    }
}

// ---------- layer-2 fused MFMA attention: 16 rows/block, 4 waves split a 256-j tile,
// adj staged coalesced into LDS, split-K atomics.
__global__ __launch_bounds__(256) void attn2_kernel(
    const float* __restrict__ adj, const unsigned short* __restrict__ whT2,
    const float* __restrict__ wh1b, const float* __restrict__ wh2b,
    const unsigned int* __restrict__ mkey2,
    float* __restrict__ out_num, float* __restrict__ out_l)
{
    __shared__ float adj_s[16][260];                 // 16.6 KB (row 1040 B, 16-aligned)
    const int b = blockIdx.z, split = blockIdx.y, i0 = blockIdx.x * 16;
    const int tid = threadIdx.x, lane = tid & 63, wv = tid >> 6;
    const int m = lane & 15, quad = lane >> 4;
    const float w1r = wh1b[(size_t)b * N_ + i0 + m];
    const float Mh = key2f(mkey2[b]);
    const float sbound = w1r + Mh;
    const float mr = fmaxf(sbound, ALPHA_ * sbound);
    const float* adjb = adj + ((size_t)b * N_ + i0) * N_;
    const float* w2g = wh2b + (size_t)b * N_;
    const unsigned short* wTg = whT2 + (size_t)b * 64 * 1024;
    f32x4 acc = {0.f, 0.f, 0.f, 0.f};
    float lsum = 0.f;
    const int jt0 = split * (N_ / S2_);              // 1024-j range, 4 tiles of 256

    for (int bt = 0; bt < (N_ / S2_) / 256; ++bt) {
        const int jT = jt0 + bt * 256;
        __syncthreads();                             // prev reads done before overwrite
#pragma unroll
        for (int r = 0; r < 4; ++r) {
            int l = r * 256 + tid;
            int row = l >> 6, c4 = (l & 63) * 4;     // one full row per wave-instr: coalesced
            *(float4*)&adj_s[row][c4] = *(const float4*)(adjb + (size_t)row * N_ + jT + c4);
        }
        __syncthreads();
        const int wbase = wv * 64;
        const int jb = split * 16 + bt * 4 + wv;
#pragma unroll
        for (int ks = 0; ks < 2; ++ks) {
            const int ko = wbase + ks * 32 + quad * 8;
            float av[8], wv8[8];
            *(float4*)&av[0] = *(const float4*)&adj_s[m][ko];
            *(float4*)&av[4] = *(const float4*)&adj_s[m][ko + 4];
            *(float4*)&wv8[0] = *(const float4*)(w2g + jT + ko);
            *(float4*)&wv8[4] = *(const float4*)(w2g + jT + ko + 4);
            bf16x8 af;
#pragma unroll
            for (int jj = 0; jj < 8; ++jj) {
                float s = w1r + wv8[jj];
                float e = fmaxf(s, ALPHA_ * s);
                float tt = (av[jj] == 0.f || s == 0.f) ? -__builtin_inff() : (e - mr);
                float p = __builtin_amdgcn_exp2f(tt);
                unsigned short pb = f2bf_rne(p);
                af[jj] = (short)pb;
                lsum += bf2f(pb);
            }
            bf16x8 b0 = *(const bf16x8*)(wTg + (size_t)jb * 1024 + m * 64 + ks * 32 + quad * 8);
            acc = __builtin_amdgcn_mfma_f32_16x16x32_bf16(af, b0, acc, 0, 0, 0);
        }
    }
#pragma unroll
    for (int reg = 0; reg < 4; ++reg) {
        int row = quad * 4 + reg;
        atomicAdd(out_num + ((size_t)b * N_ + i0 + row) * EN_ + m, acc[reg]);
    }
    lsum += __shfl_xor(lsum, 16);
    lsum += __shfl_xor(lsum, 32);
    if (quad == 0) atomicAdd(out_l + (size_t)b * N_ + i0 + m, lsum);
}

// ---------- final: out = elu(num / l)
__global__ __launch_bounds__(256) void finalize2_kernel(
    const float* __restrict__ num, const float* __restrict__ l, float* __restrict__ out)
{
    const int id = blockIdx.x * 256 + threadIdx.x;      // B*N*EN
    float v = num[id] / fmaxf(l[id >> 4], 1e-30f);
    out[id] = v > 0.f ? v : expm1f(v);
}

extern "C" void kernel_launch(void* const* d_in, const int* in_sizes, int n_in,
                              void* d_out, int out_size, void* d_ws, size_t ws_size,
                              hipStream_t stream)
{
    const float* fea = (const float*)d_in[0];
    const float* adj = (const float*)d_in[1];
    const float* Wh  = (const float*)d_in[2];
    const float* ah  = (const float*)d_in[3];
    const float* Wl  = (const float*)d_in[4];
    const float* al  = (const float*)d_in[5];

    float* ws    = (float*)d_ws;
    float* wh    = ws;                                   // B*H*N*HID = 1,048,576 f
    float* wh1   = wh   + (size_t)B_ * H_ * N_ * HID_;   // 32,768 f
    float* wh2   = wh1  + (size_t)B_ * H_ * N_;          // 32,768 f
    float* whl2  = wh2  + (size_t)B_ * H_ * N_;          // 131,072 f
    float* wh1b  = whl2 + (size_t)B_ * N_ * EN_;         // 8,192 f
    float* wh2b  = wh1b + (size_t)B_ * N_;               // 8,192 f
    // ---- zero region (single memset) ----
    float* x2num  = wh2b + (size_t)B_ * N_;              // B*N*128 = 1,048,576 f
    float* l1sum  = x2num + (size_t)B_ * N_ * D_;        // B*N*H = 32,768 f
    float* outnum = l1sum + (size_t)B_ * N_ * H_;        // B*N*EN = 131,072 f
    float* outl   = outnum + (size_t)B_ * N_ * EN_;      // B*N = 8,192 f
    unsigned int* mkey = (unsigned int*)(outl + (size_t)B_ * N_);  // 16 u32
    size_t zero_bytes = ((size_t)B_ * N_ * (D_ + H_ + EN_ + 1)) * 4 + 64;
    // ---- end zero region ----
    unsigned short* whTt  = (unsigned short*)(mkey + 16);          // 2 MB
    unsigned short* whT2t = whTt + (size_t)B_ * H_ * 64 * 2048;    // 256 KB

    hipMemsetAsync(x2num, 0, zero_bytes, stream);
    proj1_kernel<<<dim3(N_ / 8, H_, B_), 256, 0, stream>>>(fea, Wh, wh);
    proj1b_kernel<<<dim3(N_ / 128, H_, B_), 128, 0, stream>>>(wh, ah, wh1, wh2, mkey, whTt);
    attn1_kernel<<<dim3(N_ / 16, S1_, B_), 256, 0, stream>>>(adj, whTt, wh1, wh2, mkey,
                                                             x2num, l1sum);
    proj2_kernel<<<dim3(N_ / 16, B_), 256, 0, stream>>>(x2num, l1sum, Wl, whl2);
    proj2b_kernel<<<dim3(N_ / 128, B_), 128, 0, stream>>>(whl2, al, wh1b, wh2b, mkey + 8, whT2t);
    attn2_kernel<<<dim3(N_ / 16, S2_, B_), 256, 0, stream>>>(adj, whT2t, wh1b, wh2b, mkey + 8,
                                                             outnum, outl);
    finalize2_kernel<<<(B_ * N_ * EN_) / 256, 256, 0, stream>>>(outnum, outl, (float*)d_out);
}